// Round 2
// baseline (1761.270 us; speedup 1.0000x reference)
//
#include <hip/hip_runtime.h>
#include <math.h>

#define NN 13
#define BB 64
#define SS 128
#define HH 768
#define DD 512
#define GRID_NB 208

__device__ __forceinline__ float gelu_f(float x) {
    return 0.5f * x * (1.0f + erff(x * 0.7071067811865475f));
}

__device__ __forceinline__ int shape_hash(const int* __restrict__ active,
                                          const int* __restrict__ is_leaf, int b) {
    unsigned long long acc = 0ull, w = 1ull;
    for (int i = 0; i < NN; ++i) {
        unsigned long long p = (unsigned long long)(active[b*NN + i] * 2 + is_leaf[b*NN + i]);
        acc += p * w;
        w *= 31ull;
    }
    long long h = (long long)acc;
    if (h < 0) h = -h;
    return (int)(h % 256);
}

// ---------------- pool partials: one block per (unit R, s-quarter q) ----------------
// R = n*64 + b ; each block: 32 rows x 768 cols, float4 lanes (192 threads)
__global__ __launch_bounds__(192)
void pool_partial(const float* __restrict__ ls, const int* __restrict__ masks,
                  const int* __restrict__ is_leaf,
                  float* __restrict__ part, float* __restrict__ cntbuf)
{
    int idx = blockIdx.x;
    int R = idx >> 2, q = idx & 3;
    int n = R >> 6, b = R & 63;
    if (!is_leaf[b*NN + n]) return;
    const float4* src = (const float4*)(ls + (size_t)(b*NN + n) * SS * HH + (size_t)q * 32 * HH);
    const int* mk = masks + (b*NN + n) * SS + q * 32;
    int t = threadIdx.x;

    __shared__ float lsm[32];
    if (t < 32) lsm[t] = (float)mk[t];
    __syncthreads();

    float4 a = {0.f, 0.f, 0.f, 0.f};
    float cnt = 0.f;
    #pragma unroll 16
    for (int s = 0; s < 32; ++s) {
        float m = lsm[s];
        float4 v = src[s * (HH/4) + t];
        a.x += m * v.x; a.y += m * v.y; a.z += m * v.z; a.w += m * v.w;
        cnt += m;
    }
    ((float4*)(part + ((size_t)q * 832 + R) * HH))[t] = a;
    if (t == 0) cntbuf[q * 832 + R] = cnt;
}

// ---------------- device-scope grid barrier (monotonic counter) ----------------
__device__ __forceinline__ void grid_barrier(unsigned* __restrict__ cnt, unsigned target) {
    __syncthreads();
    if (threadIdx.x == 0) {
        __threadfence();                 // release our writes device-wide
        atomicAdd(cnt, 1u);              // device scope by default on global
        while (__hip_atomic_load(cnt, __ATOMIC_ACQUIRE, __HIP_MEMORY_SCOPE_AGENT) < target)
            __builtin_amdgcn_s_sleep(1);
        __threadfence();                 // acquire others' writes
    }
    __syncthreads();
}

enum { LEAF_G1 = 0, LEAF_G2 = 1, MERGE_G1 = 2, MERGE_G2 = 3, FINAL_G2 = 4 };

// 64x32 output tile, 256 threads, 2x4 micro-tile, BK=32, grid-stride over tiles.
template<int MODE>
__device__ __forceinline__ void gemm_phase(
    float (&lsA)[32][66], float (&lsB)[32][36],
    const float* __restrict__ A, const float* __restrict__ W,
    const float* __restrict__ bias, float* __restrict__ Cout,
    const int* __restrict__ is_leaf, const int* __restrict__ active,
    const int* __restrict__ depth, const int* __restrict__ left,
    const int* __restrict__ right, const float* __restrict__ depth_emb,
    const float* __restrict__ shape_emb, const float* __restrict__ noderep,
    int K, int ntiles, int n0, int n1, int n2)
{
    const int tid = threadIdx.x;
    const int tx = tid & 7, ty = tid >> 3;
    const int lane = tid & 63;

    for (int tile = blockIdx.x; tile < ntiles; tile += GRID_NB) {
        const int bx = tile & 15;
        const int by = tile >> 4;
        const int j0 = bx * 32;

        int node, lc = 0, rc = 0;
        if (MODE == LEAF_G1 || MODE == LEAF_G2) {
            node = by;
            bool anyleaf = __any(is_leaf[lane*NN + node]);
            if (!anyleaf) {
                if (MODE == LEAF_G2) {   // still must zero-init noderep column
                    const int r0 = 2*ty, r1 = r0 + 1;
                    float* dst = Cout + (size_t)(node*64)*DD;
                    #pragma unroll
                    for (int j = 0; j < 4; ++j) {
                        int jc = j0 + tx*4 + j;
                        dst[(size_t)r0*DD + jc] = 0.f;
                        dst[(size_t)r1*DD + jc] = 0.f;
                    }
                }
                continue;
            }
        } else {
            node = (by == 0) ? n0 : ((by == 1) ? n1 : n2);
            if (MODE == MERGE_G1) { lc = left[node]; rc = right[node]; }
        }

        float acc[2][4] = {{0,0,0,0},{0,0,0,0}};

        for (int k0 = 0; k0 < K; k0 += 32) {
            #pragma unroll
            for (int i = 0; i < 8; ++i) {           // stage A: 64x32
                int e = i*256 + tid;
                int r = e >> 5, k = e & 31;
                float v;
                if (MODE == LEAF_G1) {
                    v = is_leaf[r*NN + node] ? A[(size_t)(node*64 + r)*HH + k0 + k] : 0.f;
                } else if (MODE == LEAF_G2) {
                    v = A[(size_t)(node*64 + r)*DD + k0 + k];
                } else if (MODE == MERGE_G1) {
                    int kg = k0 + k;
                    v = (kg < DD) ? noderep[(size_t)(lc*64 + r)*DD + kg]
                                  : noderep[(size_t)(rc*64 + r)*DD + (kg - DD)];
                } else {  // MERGE_G2 / FINAL_G2: A = mhid indexed by slot
                    v = A[(size_t)(by*64 + r)*DD + k0 + k];
                }
                lsA[k][r] = v;
            }
            #pragma unroll
            for (int i = 0; i < 4; ++i) {           // stage B: 32x32
                int e = i*256 + tid;
                int kr = e >> 5, c = e & 31;
                lsB[kr][c] = W[(size_t)(k0 + kr)*DD + j0 + c];
            }
            __syncthreads();
            #pragma unroll
            for (int kk = 0; kk < 32; ++kk) {
                float2 a2 = *(const float2*)&lsA[kk][2*ty];
                float4 b4 = *(const float4*)&lsB[kk][tx*4];
                acc[0][0] += a2.x * b4.x; acc[0][1] += a2.x * b4.y;
                acc[0][2] += a2.x * b4.z; acc[0][3] += a2.x * b4.w;
                acc[1][0] += a2.y * b4.x; acc[1][1] += a2.y * b4.y;
                acc[1][2] += a2.y * b4.z; acc[1][3] += a2.y * b4.w;
            }
            __syncthreads();
        }

        const int r0 = 2*ty, r1 = r0 + 1;

        if (MODE == LEAF_G1) {
            float* dst = Cout + (size_t)(node*64)*DD;
            #pragma unroll
            for (int j = 0; j < 4; ++j) {
                int jc = j0 + tx*4 + j;
                dst[(size_t)r0*DD + jc] = gelu_f(acc[0][j] + bias[jc]);
                dst[(size_t)r1*DD + jc] = gelu_f(acc[1][j] + bias[jc]);
            }
        } else if (MODE == LEAF_G2) {
            int dp = depth[node];
            const float* de = depth_emb + (size_t)dp*DD;
            bool lf0 = is_leaf[r0*NN + node] != 0;
            bool lf1 = is_leaf[r1*NN + node] != 0;
            float* dst = Cout + (size_t)(node*64)*DD;
            #pragma unroll
            for (int j = 0; j < 4; ++j) {
                int jc = j0 + tx*4 + j;
                dst[(size_t)r0*DD + jc] = lf0 ? (acc[0][j] + bias[jc] + de[jc]) : 0.f;
                dst[(size_t)r1*DD + jc] = lf1 ? (acc[1][j] + bias[jc] + de[jc]) : 0.f;
            }
        } else if (MODE == MERGE_G1) {
            float* dst = Cout + (size_t)(by*64)*DD;   // mhid, by slot
            #pragma unroll
            for (int j = 0; j < 4; ++j) {
                int jc = j0 + tx*4 + j;
                dst[(size_t)r0*DD + jc] = gelu_f(acc[0][j] + bias[jc]);
                dst[(size_t)r1*DD + jc] = gelu_f(acc[1][j] + bias[jc]);
            }
        } else {
            int dp = depth[node];
            const float* de = depth_emb + (size_t)dp*DD;
            bool anyInt = __any(active[lane*NN + node] && !is_leaf[lane*NN + node]);
            bool i0 = active[r0*NN + node] && !is_leaf[r0*NN + node];
            bool i1 = active[r1*NN + node] && !is_leaf[r1*NN + node];
            const float* nrep = noderep + (size_t)(node*64)*DD;
            if (MODE == MERGE_G2) {
                float* dst = Cout + (size_t)(node*64)*DD;
                #pragma unroll
                for (int j = 0; j < 4; ++j) {
                    int jc = j0 + tx*4 + j;
                    float m0 = acc[0][j] + bias[jc] + de[jc];
                    float m1 = acc[1][j] + bias[jc] + de[jc];
                    float c0 = anyInt ? (i0 ? m0 : 0.f) : nrep[(size_t)r0*DD + jc];
                    float c1 = anyInt ? (i1 ? m1 : 0.f) : nrep[(size_t)r1*DD + jc];
                    dst[(size_t)r0*DD + jc] = c0;
                    dst[(size_t)r1*DD + jc] = c1;
                }
            } else {  // FINAL_G2
                int h0 = shape_hash(active, is_leaf, r0);
                int h1 = shape_hash(active, is_leaf, r1);
                #pragma unroll
                for (int j = 0; j < 4; ++j) {
                    int jc = j0 + tx*4 + j;
                    float m0 = acc[0][j] + bias[jc] + de[jc];
                    float m1 = acc[1][j] + bias[jc] + de[jc];
                    float c0 = anyInt ? (i0 ? m0 : 0.f) : nrep[(size_t)r0*DD + jc];
                    float c1 = anyInt ? (i1 ? m1 : 0.f) : nrep[(size_t)r1*DD + jc];
                    Cout[(size_t)r0*DD + jc] = c0 + shape_emb[(size_t)h0*DD + jc];
                    Cout[(size_t)r1*DD + jc] = c1 + shape_emb[(size_t)h1*DD + jc];
                }
            }
        }
    }
}

__global__ __launch_bounds__(256, 2)
void mega_kernel(float* __restrict__ pooled, const float* __restrict__ cntbuf,
                 const float* __restrict__ part,
                 const int* __restrict__ is_leaf, const int* __restrict__ active,
                 const int* __restrict__ depth, const int* __restrict__ left,
                 const int* __restrict__ right,
                 const float* __restrict__ Wl1, const float* __restrict__ bl1,
                 const float* __restrict__ Wl2, const float* __restrict__ bl2,
                 const float* __restrict__ Wm1, const float* __restrict__ bm1,
                 const float* __restrict__ Wm2, const float* __restrict__ bm2,
                 const float* __restrict__ depth_emb, const float* __restrict__ shape_emb,
                 float* __restrict__ hidden, float* __restrict__ noderep,
                 float* __restrict__ mhid, float* __restrict__ out,
                 unsigned* __restrict__ barrier_cnt)
{
    __shared__ __align__(16) float lsA[32][66];
    __shared__ __align__(16) float lsB[32][36];
    const int tid = threadIdx.x;

    // phase 0: combine pool partials -> pooled
    for (int u = blockIdx.x; u < 832; u += GRID_NB) {
        int n = u >> 6, b = u & 63;
        if (!is_leaf[b*NN + n]) continue;
        if (tid < 192) {
            float cnt = cntbuf[u] + cntbuf[832 + u] + cntbuf[1664 + u] + cntbuf[2496 + u];
            float inv = 1.f / fmaxf(cnt, 1.f);
            float4 s = {0.f, 0.f, 0.f, 0.f};
            #pragma unroll
            for (int q = 0; q < 4; ++q) {
                float4 v = ((const float4*)(part + ((size_t)q * 832 + u) * HH))[tid];
                s.x += v.x; s.y += v.y; s.z += v.z; s.w += v.w;
            }
            s.x *= inv; s.y *= inv; s.z *= inv; s.w *= inv;
            ((float4*)(pooled + (size_t)u * HH))[tid] = s;
        }
    }
    grid_barrier(barrier_cnt, GRID_NB * 1);

    gemm_phase<LEAF_G1>(lsA, lsB, pooled, Wl1, bl1, hidden,
                        is_leaf, active, depth, left, right, depth_emb, shape_emb, noderep,
                        HH, 13*16, 0, 0, 0);
    grid_barrier(barrier_cnt, GRID_NB * 2);

    gemm_phase<LEAF_G2>(lsA, lsB, hidden, Wl2, bl2, noderep,
                        is_leaf, active, depth, left, right, depth_emb, shape_emb, noderep,
                        DD, 13*16, 0, 0, 0);
    grid_barrier(barrier_cnt, GRID_NB * 3);

    gemm_phase<MERGE_G1>(lsA, lsB, noderep, Wm1, bm1, mhid,
                         is_leaf, active, depth, left, right, depth_emb, shape_emb, noderep,
                         2*DD, 3*16, 3, 4, 5);
    grid_barrier(barrier_cnt, GRID_NB * 4);

    gemm_phase<MERGE_G2>(lsA, lsB, mhid, Wm2, bm2, noderep,
                         is_leaf, active, depth, left, right, depth_emb, shape_emb, noderep,
                         DD, 3*16, 3, 4, 5);
    grid_barrier(barrier_cnt, GRID_NB * 5);

    gemm_phase<MERGE_G1>(lsA, lsB, noderep, Wm1, bm1, mhid,
                         is_leaf, active, depth, left, right, depth_emb, shape_emb, noderep,
                         2*DD, 2*16, 1, 2, 0);
    grid_barrier(barrier_cnt, GRID_NB * 6);

    gemm_phase<MERGE_G2>(lsA, lsB, mhid, Wm2, bm2, noderep,
                         is_leaf, active, depth, left, right, depth_emb, shape_emb, noderep,
                         DD, 2*16, 1, 2, 0);
    grid_barrier(barrier_cnt, GRID_NB * 7);

    gemm_phase<MERGE_G1>(lsA, lsB, noderep, Wm1, bm1, mhid,
                         is_leaf, active, depth, left, right, depth_emb, shape_emb, noderep,
                         2*DD, 1*16, 0, 0, 0);
    grid_barrier(barrier_cnt, GRID_NB * 8);

    gemm_phase<FINAL_G2>(lsA, lsB, mhid, Wm2, bm2, out,
                         is_leaf, active, depth, left, right, depth_emb, shape_emb, noderep,
                         DD, 1*16, 0, 0, 0);
}

extern "C" void kernel_launch(void* const* d_in, const int* in_sizes, int n_in,
                              void* d_out, int out_size, void* d_ws, size_t ws_size,
                              hipStream_t stream)
{
    const int*   is_leaf     = (const int*)d_in[0];
    const int*   active      = (const int*)d_in[1];
    const int*   depth       = (const int*)d_in[2];
    const int*   left        = (const int*)d_in[3];
    const int*   right       = (const int*)d_in[4];
    const float* leaf_states = (const float*)d_in[5];
    const int*   leaf_masks  = (const int*)d_in[6];
    const float* Wl1 = (const float*)d_in[7];
    const float* bl1 = (const float*)d_in[8];
    const float* Wl2 = (const float*)d_in[9];
    const float* bl2 = (const float*)d_in[10];
    const float* Wm1 = (const float*)d_in[11];
    const float* bm1 = (const float*)d_in[12];
    const float* Wm2 = (const float*)d_in[13];
    const float* bm2 = (const float*)d_in[14];
    const float* depth_emb = (const float*)d_in[15];
    const float* shape_emb = (const float*)d_in[16];
    float* out = (float*)d_out;
    float* ws  = (float*)d_ws;

    // ws layout (floats)
    float* part    = ws;                        // 4*832*768
    float* cntbuf  = part + 4*832*768;          // 4*832
    float* pooled  = cntbuf + 4*832;            // 832*768
    float* hidden  = pooled + 832*768;          // 832*512
    float* noderep = hidden + 832*512;          // 832*512
    float* mhid    = noderep + 832*512;         // 3*64*512
    unsigned* barrier_cnt = (unsigned*)(mhid + 3*64*512);

    hipMemsetAsync(barrier_cnt, 0, sizeof(unsigned), stream);

    pool_partial<<<dim3(832*4), 192, 0, stream>>>(leaf_states, leaf_masks, is_leaf,
                                                  part, cntbuf);

    mega_kernel<<<dim3(GRID_NB), 256, 0, stream>>>(
        pooled, cntbuf, part, is_leaf, active, depth, left, right,
        Wl1, bl1, Wl2, bl2, Wm1, bm1, Wm2, bm2, depth_emb, shape_emb,
        hidden, noderep, mhid, out, barrier_cnt);
}

// Round 3
// 121.588 us; speedup vs baseline: 14.4856x; 14.4856x over previous
//
#include <hip/hip_runtime.h>
#include <hip/hip_bf16.h>
#include <math.h>

#define NN 13
#define SS 128
#define HH 768
#define DD 512

typedef __attribute__((ext_vector_type(8))) short bf16x8;
typedef __attribute__((ext_vector_type(4))) float f32x4;

__device__ __forceinline__ float gelu_f(float x) {
    return 0.5f * x * (1.0f + erff(x * 0.7071067811865475f));
}
__device__ __forceinline__ ushort f2b(float v) {
    __hip_bfloat16 h = __float2bfloat16(v);
    return *reinterpret_cast<ushort*>(&h);
}
__device__ __forceinline__ float b2f(ushort u) {
    __hip_bfloat16 h = *reinterpret_cast<__hip_bfloat16*>(&u);
    return __bfloat162float(h);
}

__device__ __forceinline__ int shape_hash(const int* __restrict__ active,
                                          const int* __restrict__ is_leaf, int b) {
    unsigned long long acc = 0ull, w = 1ull;
    for (int i = 0; i < NN; ++i) {
        unsigned long long p = (unsigned long long)(active[b*NN + i] * 2 + is_leaf[b*NN + i]);
        acc += p * w;
        w *= 31ull;
    }
    long long h = (long long)acc;
    if (h < 0) h = -h;
    return (int)(h % 256);
}

// ---------- weight transpose + bf16 cast: W[K][512] f32 -> WT[512][K] bf16 ----------
__global__ __launch_bounds__(256)
void transpose_weights(const float* __restrict__ Wl1, const float* __restrict__ Wl2,
                       const float* __restrict__ Wm1, const float* __restrict__ Wm2,
                       ushort* __restrict__ Tl1, ushort* __restrict__ Tl2,
                       ushort* __restrict__ Tm1, ushort* __restrict__ Tm2)
{
    int bx = blockIdx.x;
    const float* W; ushort* T; int K, tile;
    if (bx < 384)       { W = Wl1; T = Tl1; K = 768;  tile = bx; }
    else if (bx < 640)  { W = Wl2; T = Tl2; K = 512;  tile = bx - 384; }
    else if (bx < 1152) { W = Wm1; T = Tm1; K = 1024; tile = bx - 640; }
    else                { W = Wm2; T = Tm2; K = 512;  tile = bx - 1152; }
    int tk = tile >> 4, tj = tile & 15;
    __shared__ float lds[32][33];
    int t = threadIdx.x;
    int r = t >> 3, c0 = (t & 7) * 4;
    const float4 v = *(const float4*)(W + (size_t)(tk*32 + r)*DD + tj*32 + c0);
    lds[r][c0+0] = v.x; lds[r][c0+1] = v.y; lds[r][c0+2] = v.z; lds[r][c0+3] = v.w;
    __syncthreads();
    ushort* dst = T + (size_t)(tj*32 + r)*K + tk*32 + c0;
    dst[0] = f2b(lds[c0+0][r]); dst[1] = f2b(lds[c0+1][r]);
    dst[2] = f2b(lds[c0+2][r]); dst[3] = f2b(lds[c0+3][r]);
}

// ---------- pool partials: block = (unit R, s-quarter q); 192 thr, float4 lanes ----------
__global__ __launch_bounds__(192)
void pool_partial(const float* __restrict__ ls, const int* __restrict__ masks,
                  const int* __restrict__ is_leaf,
                  float* __restrict__ part, float* __restrict__ cntbuf)
{
    int idx = blockIdx.x;
    int R = idx >> 2, q = idx & 3;
    int n = R >> 6, b = R & 63;
    if (!is_leaf[b*NN + n]) return;
    const float4* src = (const float4*)(ls + (size_t)(b*NN + n) * SS * HH + (size_t)q * 32 * HH);
    const int* mk = masks + (b*NN + n) * SS + q * 32;
    int t = threadIdx.x;

    __shared__ float lsm[32];
    if (t < 32) lsm[t] = (float)mk[t];
    __syncthreads();

    float4 a = {0.f, 0.f, 0.f, 0.f};
    float cnt = 0.f;
    #pragma unroll 16
    for (int s = 0; s < 32; ++s) {
        float m = lsm[s];
        float4 v = src[s * (HH/4) + t];
        a.x += m * v.x; a.y += m * v.y; a.z += m * v.z; a.w += m * v.w;
        cnt += m;
    }
    ((float4*)(part + ((size_t)q * 832 + R) * HH))[t] = a;
    if (t == 0) cntbuf[q * 832 + R] = cnt;
}

// ---------- combine partials -> pooled (bf16); zeros for non-leaf units ----------
__global__ __launch_bounds__(192)
void pool_combine(const float* __restrict__ part, const float* __restrict__ cntbuf,
                  const int* __restrict__ is_leaf, ushort* __restrict__ pooled)
{
    int u = blockIdx.x;  // 0..831
    int n = u >> 6, b = u & 63;
    int t = threadIdx.x;
    ushort4* dst = (ushort4*)(pooled + (size_t)u * HH);
    if (!is_leaf[b*NN + n]) {
        ushort4 z = {0, 0, 0, 0};
        dst[t] = z;
        return;
    }
    float cnt = cntbuf[u] + cntbuf[832+u] + cntbuf[1664+u] + cntbuf[2496+u];
    float inv = 1.f / fmaxf(cnt, 1.f);
    float4 s = {0.f, 0.f, 0.f, 0.f};
    #pragma unroll
    for (int q = 0; q < 4; ++q) {
        float4 v = ((const float4*)(part + ((size_t)q * 832 + u) * HH))[t];
        s.x += v.x; s.y += v.y; s.z += v.z; s.w += v.w;
    }
    ushort4 o = { f2b(s.x*inv), f2b(s.y*inv), f2b(s.z*inv), f2b(s.w*inv) };
    dst[t] = o;
}

enum { LEAF_G1 = 0, LEAF_G2 = 1, MERGE_G1 = 2, MERGE_G2 = 3, FINAL_G2 = 4 };

// MFMA GEMM: block = 64 rows (one node/slot) x 64 cols; 4 waves; BK=32 double-buffered.
template<int MODE, int KT>
__global__ __launch_bounds__(256)
void mfma_gemm(const ushort* __restrict__ Asrc, const ushort* __restrict__ WT,
               const float* __restrict__ bias, void* __restrict__ CoutV,
               const int* __restrict__ is_leaf, const int* __restrict__ active,
               const int* __restrict__ depth, const int* __restrict__ left,
               const int* __restrict__ right,
               const float* __restrict__ depth_emb, const float* __restrict__ shape_emb,
               const ushort* __restrict__ noderep,
               int n0, int n1, int n2)
{
    constexpr int NITER = KT / 32;
    __shared__ ushort a_lds[2][64*40];
    __shared__ ushort b_lds[2][64*40];

    const int t = threadIdx.x;
    const int lane = t & 63, wv = t >> 6;
    const int j0 = blockIdx.x * 64;
    const int by = blockIdx.y;
    const int lrow = lane & 15, lhi = lane >> 4;

    int node, lc = 0, rc = 0;
    if (MODE == LEAF_G1 || MODE == LEAF_G2) {
        node = by;
        bool anyleaf = __any(is_leaf[lane*NN + node] != 0);
        if (!anyleaf) {
            if (MODE == LEAF_G2) {           // zero-init this noderep column
                ushort* dst = (ushort*)CoutV + (size_t)(node*64)*DD;
                #pragma unroll
                for (int c = 0; c < 4; ++c) {
                    int jc = j0 + c*16 + lrow;
                    #pragma unroll
                    for (int reg = 0; reg < 4; ++reg) {
                        int rw = wv*16 + lhi*4 + reg;
                        dst[(size_t)rw*DD + jc] = 0;
                    }
                }
            }
            return;
        }
    } else {
        node = (by == 0) ? n0 : ((by == 1) ? n1 : n2);
        lc = left[node]; rc = right[node];
    }

    const int AK = (MODE == LEAF_G1) ? HH : DD;
    const int rowbase = (MODE == LEAF_G1 || MODE == LEAF_G2) ? node*64
                       : (MODE == MERGE_G1) ? 0 : by*64;

    const int sr = t >> 2, skg = t & 3;
    f32x4 acc[4];
    #pragma unroll
    for (int c = 0; c < 4; ++c) acc[c] = (f32x4){0.f, 0.f, 0.f, 0.f};

    uint4 aReg, bReg;
    auto loadAB = [&](int kt) {
        int k0 = kt*32 + skg*8;
        const ushort* ap;
        if (MODE == MERGE_G1) {
            ap = (k0 < DD) ? noderep + (size_t)(lc*64 + sr)*DD + k0
                           : noderep + (size_t)(rc*64 + sr)*DD + (k0 - DD);
        } else {
            ap = Asrc + (size_t)(rowbase + sr)*AK + k0;
        }
        aReg = *(const uint4*)ap;
        bReg = *(const uint4*)(WT + (size_t)(j0 + sr)*KT + k0);
    };
    auto storeAB = [&](int buf) {
        *(uint4*)&a_lds[buf][sr*40 + skg*8] = aReg;
        *(uint4*)&b_lds[buf][sr*40 + skg*8] = bReg;
    };

    loadAB(0);
    storeAB(0);
    __syncthreads();

    for (int kt = 0; kt < NITER; ++kt) {
        if (kt + 1 < NITER) loadAB(kt + 1);
        const int buf = kt & 1;
        bf16x8 af = *(const bf16x8*)&a_lds[buf][(wv*16 + lrow)*40 + lhi*8];
        #pragma unroll
        for (int c = 0; c < 4; ++c) {
            bf16x8 bfr = *(const bf16x8*)&b_lds[buf][(c*16 + lrow)*40 + lhi*8];
            acc[c] = __builtin_amdgcn_mfma_f32_16x16x32_bf16(af, bfr, acc[c], 0, 0, 0);
        }
        if (kt + 1 < NITER) storeAB(buf ^ 1);
        __syncthreads();
    }

    // ---------------- epilogue ----------------
    if (MODE == LEAF_G1) {
        ushort* H = (ushort*)CoutV + (size_t)(node*64)*DD;
        #pragma unroll
        for (int c = 0; c < 4; ++c) {
            int jc = j0 + c*16 + lrow;
            float bj = bias[jc];
            #pragma unroll
            for (int reg = 0; reg < 4; ++reg) {
                int rw = wv*16 + lhi*4 + reg;
                H[(size_t)rw*DD + jc] = f2b(gelu_f(acc[c][reg] + bj));
            }
        }
    } else if (MODE == LEAF_G2) {
        int dp = depth[node];
        const float* de = depth_emb + (size_t)dp*DD;
        bool lf[4];
        #pragma unroll
        for (int reg = 0; reg < 4; ++reg)
            lf[reg] = is_leaf[(wv*16 + lhi*4 + reg)*NN + node] != 0;
        ushort* dst = (ushort*)CoutV + (size_t)(node*64)*DD;
        #pragma unroll
        for (int c = 0; c < 4; ++c) {
            int jc = j0 + c*16 + lrow;
            float bj = bias[jc] + de[jc];
            #pragma unroll
            for (int reg = 0; reg < 4; ++reg) {
                int rw = wv*16 + lhi*4 + reg;
                dst[(size_t)rw*DD + jc] = f2b(lf[reg] ? (acc[c][reg] + bj) : 0.f);
            }
        }
    } else if (MODE == MERGE_G1) {
        ushort* Mh = (ushort*)CoutV + (size_t)(by*64)*DD;
        #pragma unroll
        for (int c = 0; c < 4; ++c) {
            int jc = j0 + c*16 + lrow;
            float bj = bias[jc];
            #pragma unroll
            for (int reg = 0; reg < 4; ++reg) {
                int rw = wv*16 + lhi*4 + reg;
                Mh[(size_t)rw*DD + jc] = f2b(gelu_f(acc[c][reg] + bj));
            }
        }
    } else {
        int dp = depth[node];
        const float* de = depth_emb + (size_t)dp*DD;
        bool anyInt = __any(active[lane*NN + node] && !is_leaf[lane*NN + node]);
        bool iv[4];
        #pragma unroll
        for (int reg = 0; reg < 4; ++reg) {
            int rw = wv*16 + lhi*4 + reg;
            iv[reg] = active[rw*NN + node] && !is_leaf[rw*NN + node];
        }
        if (MODE == MERGE_G2) {
            if (!anyInt) return;             // keep existing noderep column
            ushort* dst = (ushort*)CoutV + (size_t)(node*64)*DD;
            #pragma unroll
            for (int c = 0; c < 4; ++c) {
                int jc = j0 + c*16 + lrow;
                float bj = bias[jc] + de[jc];
                #pragma unroll
                for (int reg = 0; reg < 4; ++reg) {
                    int rw = wv*16 + lhi*4 + reg;
                    dst[(size_t)rw*DD + jc] = f2b(iv[reg] ? (acc[c][reg] + bj) : 0.f);
                }
            }
        } else {  // FINAL_G2 -> f32 out + shape_emb
            float* out = (float*)CoutV;
            int hh[4];
            #pragma unroll
            for (int reg = 0; reg < 4; ++reg)
                hh[reg] = shape_hash(active, is_leaf, wv*16 + lhi*4 + reg);
            #pragma unroll
            for (int c = 0; c < 4; ++c) {
                int jc = j0 + c*16 + lrow;
                float bj = bias[jc] + de[jc];
                #pragma unroll
                for (int reg = 0; reg < 4; ++reg) {
                    int rw = wv*16 + lhi*4 + reg;
                    float base = anyInt ? (iv[reg] ? (acc[c][reg] + bj) : 0.f)
                                        : b2f(noderep[(size_t)(node*64 + rw)*DD + jc]);
                    out[(size_t)rw*DD + jc] = base + shape_emb[(size_t)hh[reg]*DD + jc];
                }
            }
        }
    }
}

extern "C" void kernel_launch(void* const* d_in, const int* in_sizes, int n_in,
                              void* d_out, int out_size, void* d_ws, size_t ws_size,
                              hipStream_t stream)
{
    const int*   is_leaf     = (const int*)d_in[0];
    const int*   active      = (const int*)d_in[1];
    const int*   depth       = (const int*)d_in[2];
    const int*   left        = (const int*)d_in[3];
    const int*   right       = (const int*)d_in[4];
    const float* leaf_states = (const float*)d_in[5];
    const int*   leaf_masks  = (const int*)d_in[6];
    const float* Wl1 = (const float*)d_in[7];
    const float* bl1 = (const float*)d_in[8];
    const float* Wl2 = (const float*)d_in[9];
    const float* bl2 = (const float*)d_in[10];
    const float* Wm1 = (const float*)d_in[11];
    const float* bm1 = (const float*)d_in[12];
    const float* Wm2 = (const float*)d_in[13];
    const float* bm2 = (const float*)d_in[14];
    const float* depth_emb = (const float*)d_in[15];
    const float* shape_emb = (const float*)d_in[16];
    float* out = (float*)d_out;

    // ws layout: f32 region first, then bf16 (ushort) region; all 16B-aligned
    float* part   = (float*)d_ws;                 // 4*832*768 f32
    float* cntbuf = part + 4*832*768;             // 4*832 f32
    ushort* pooled  = (ushort*)(cntbuf + 4*832);  // 832*768 bf16
    ushort* hidden  = pooled + 832*768;           // 832*512
    ushort* noderep = hidden + 832*512;           // 832*512
    ushort* mhid    = noderep + 832*512;          // 3*64*512
    ushort* Tl1 = mhid + 3*64*512;                // 512*768
    ushort* Tl2 = Tl1 + 512*768;                  // 512*512
    ushort* Tm1 = Tl2 + 512*512;                  // 512*1024
    ushort* Tm2 = Tm1 + 512*1024;                 // 512*512

    transpose_weights<<<1408, 256, 0, stream>>>(Wl1, Wl2, Wm1, Wm2, Tl1, Tl2, Tm1, Tm2);

    pool_partial<<<832*4, 192, 0, stream>>>(leaf_states, leaf_masks, is_leaf, part, cntbuf);
    pool_combine<<<832, 192, 0, stream>>>(part, cntbuf, is_leaf, pooled);

    // leaf MLP (all nodes; no-leaf nodes short-circuit / zero-fill)
    mfma_gemm<LEAF_G1, 768><<<dim3(8, 13), 256, 0, stream>>>(
        pooled, Tl1, bl1, hidden, is_leaf, active, depth, left, right,
        depth_emb, shape_emb, noderep, 0, 0, 0);
    mfma_gemm<LEAF_G2, 512><<<dim3(8, 13), 256, 0, stream>>>(
        hidden, Tl2, bl2, noderep, is_leaf, active, depth, left, right,
        depth_emb, shape_emb, noderep, 0, 0, 0);

    // merge level 1: nodes {3,4,5}
    mfma_gemm<MERGE_G1, 1024><<<dim3(8, 3), 256, 0, stream>>>(
        nullptr, Tm1, bm1, mhid, is_leaf, active, depth, left, right,
        depth_emb, shape_emb, noderep, 3, 4, 5);
    mfma_gemm<MERGE_G2, 512><<<dim3(8, 3), 256, 0, stream>>>(
        mhid, Tm2, bm2, noderep, is_leaf, active, depth, left, right,
        depth_emb, shape_emb, noderep, 3, 4, 5);

    // merge level 2: nodes {1,2}
    mfma_gemm<MERGE_G1, 1024><<<dim3(8, 2), 256, 0, stream>>>(
        nullptr, Tm1, bm1, mhid, is_leaf, active, depth, left, right,
        depth_emb, shape_emb, noderep, 1, 2, 0);
    mfma_gemm<MERGE_G2, 512><<<dim3(8, 2), 256, 0, stream>>>(
        mhid, Tm2, bm2, noderep, is_leaf, active, depth, left, right,
        depth_emb, shape_emb, noderep, 1, 2, 0);

    // merge level 3: node {0} -> fused hash + shape_emb + f32 output
    mfma_gemm<MERGE_G1, 1024><<<dim3(8, 1), 256, 0, stream>>>(
        nullptr, Tm1, bm1, mhid, is_leaf, active, depth, left, right,
        depth_emb, shape_emb, noderep, 0, 0, 0);
    mfma_gemm<FINAL_G2, 512><<<dim3(8, 1), 256, 0, stream>>>(
        mhid, Tm2, bm2, out, is_leaf, active, depth, left, right,
        depth_emb, shape_emb, noderep, 0, 0, 0);
}